// Round 16
// baseline (203.866 us; speedup 1.0000x reference)
//
#include <hip/hip_runtime.h>
#include <hip/hip_bf16.h>
#include <stdint.h>

typedef unsigned char u8;
typedef unsigned int u32;
typedef unsigned long long u64;
typedef long i64;
typedef i64 i64x2 __attribute__((ext_vector_type(2)));
typedef float f32x4 __attribute__((ext_vector_type(4)));

#define LOGSQRT2PI 0.9189385332046727f
#define SB0() __builtin_amdgcn_sched_barrier(0)
#define MFMA8(A, B, C) __builtin_amdgcn_mfma_f32_16x16x32_fp8_fp8(A, B, C, 0, 0, 0)

__device__ __forceinline__ void gload_lds16(const void* g, void* l) {
    __builtin_amdgcn_global_load_lds((__attribute__((address_space(1))) void*)g,
                                     (__attribute__((address_space(3))) void*)l,
                                     16, 0, 0);
}

__device__ __forceinline__ u8 to_fp8(float v) {
    return (u8)(__builtin_amdgcn_cvt_pk_fp8_f32(v, 0.f, 0, false) & 0xff);
}

// pack 4 float4 (16 consecutive fp32) -> 16B fp8 fragment, bytes k ascending
__device__ __forceinline__ i64x2 pack_frag(const float4* v) {
    u32 w0 = __builtin_amdgcn_cvt_pk_fp8_f32(v[0].x, v[0].y, 0, false);
    w0 = __builtin_amdgcn_cvt_pk_fp8_f32(v[0].z, v[0].w, (int)w0, true);
    u32 w1 = __builtin_amdgcn_cvt_pk_fp8_f32(v[1].x, v[1].y, 0, false);
    w1 = __builtin_amdgcn_cvt_pk_fp8_f32(v[1].z, v[1].w, (int)w1, true);
    u32 w2 = __builtin_amdgcn_cvt_pk_fp8_f32(v[2].x, v[2].y, 0, false);
    w2 = __builtin_amdgcn_cvt_pk_fp8_f32(v[2].z, v[2].w, (int)w2, true);
    u32 w3 = __builtin_amdgcn_cvt_pk_fp8_f32(v[3].x, v[3].y, 0, false);
    w3 = __builtin_amdgcn_cvt_pk_fp8_f32(v[3].z, v[3].w, (int)w3, true);
    i64x2 rr;
    rr.x = (i64)(((u64)w1 << 32) | (u64)w0);
    rr.y = (i64)(((u64)w3 << 32) | (u64)w2);
    return rr;
}

// ---- merged weight prep (r12-proven math; grid 1040 for 2x TLP) ----
__device__ __forceinline__ void prep_body(const float* __restrict__ mu,
        const float* __restrict__ p, const float* __restrict__ eps,
        u8* __restrict__ Wt, int N, int Npad, float* __restrict__ osc,
        int vb, int nblocks) {
    int total = 512 * Npad;
    float lqw = 0.f, lpw = 0.f;
    for (int idx = vb * 256 + threadIdx.x; idx < total; idx += nblocks * 256) {
        int k = idx / Npad, n = idx - k * Npad;
        float w = 0.f;
        if (n < N) {
            int src = k * N + n;
            float m = mu[src], e = eps[src];
            float sd = 1e-6f + log1pf(expf(p[src]));
            w = m + sd * e;
            float z = (w - m) / sd;
            lqw += -LOGSQRT2PI - logf(sd) - 0.5f * z * z;
            lpw += -LOGSQRT2PI - 0.5f * w * w;
        }
        Wt[n * 512 + k] = to_fp8(w);
    }
    #pragma unroll
    for (int off = 32; off; off >>= 1) {
        lqw += __shfl_down(lqw, off);
        lpw += __shfl_down(lpw, off);
    }
    if ((threadIdx.x & 63) == 0) {
        atomicAdd(&osc[0], lqw);
        atomicAdd(&osc[1], lpw);
    }
}

__global__ void k_prep_all(const float* __restrict__ mu1, const float* __restrict__ p1,
                           const float* __restrict__ e1,
                           const float* __restrict__ mu2, const float* __restrict__ p2,
                           const float* __restrict__ e2,
                           const float* __restrict__ mu3, const float* __restrict__ p3,
                           const float* __restrict__ e3,
                           u8* __restrict__ Wt1, u8* __restrict__ Wt2,
                           u8* __restrict__ Wt3, float* __restrict__ osc) {
    int b = blockIdx.x;
    if (b < 512)       prep_body(mu1, p1, e1, Wt1, 512, 512, osc, b, 512);
    else if (b < 1024) prep_body(mu2, p2, e2, Wt2, 512, 512, osc, b - 512, 512);
    else               prep_body(mu3, p3, e3, Wt3, 10,  16,  osc, b - 1024, 16);
}

// ============================================================================
// Fully-fused fp8 3-layer kernel, v3 (r15 + X/compute overlap).
//   Layer 1 split into pass A (rows 0-15/wave) and pass B (rows 16-31):
//   only xfA is needed to start -> xfB's 64 MB HBM burst is issued after the
//   first barrier and streams UNDER pass-A's MFMA phases; cvt'd in two static
//   quads (all indices compile-time -> registers, rule #20).
//   xfA loads as two fully-issued 64-VGPR quads (BW-bound, not latency-chained).
//   W-tiles 64-col, double-buffered; stage(next) at phase start, vmcnt(0) at
//   phase end (r15-proven).  Pass A re-stages W1 for pass B (L2-hot, cheap).
//   h1 in registers via wave-private swizzled scr (phys_chunk = jg^(row&7));
//   layer 2 combined-rowgroup GLOOP (4 MFMA per B-frag read); layer 3 fused;
//   y stored directly.  LDS 80 KB -> 2 blocks/CU; setprio(1) around GLOOPs.
// ============================================================================
__global__ __launch_bounds__(256, 2)
void k_f8(const float* __restrict__ X, const u8* __restrict__ W1t,
          const u8* __restrict__ W2t, const u8* __restrict__ W3t,
          float* __restrict__ Y) {
    __shared__ __align__(16) u8 L[81920];   // 2x32KB Wbuf + 4x4KB scr
    const int tid = threadIdx.x;
    const int l = tid & 63, w = tid >> 6;
    const int r = l & 15, kq = l >> 4;
    const int l16 = l * 16;
    const long m0 = (long)blockIdx.x * 128 + w * 32;
    u8* scr = &L[65536 + w * 4096];

    #define STAGEW(WT, NT, BUF) { _Pragma("unroll")                            \
        for (int i = 0; i < 8; i++) {                                          \
            const int c = w * 8 + i;                                           \
            const int jg = c & 3, kt = c >> 2;                                 \
            gload_lds16((WT) + ((NT) * 64 + jg * 16 + r) * 512 + kt * 64 + kq * 16, \
                        &L[(BUF) * 32768 + c * 1024 + l16]);                   \
        } }

    f32x4 accA[4], accB[4];
    i64x2 xfA[8], xfB[8];
    i64x2 h1fA[8], h1fB[8];
    f32x4 yA = (f32x4){0.f, 0.f, 0.f, 0.f};
    f32x4 yB = (f32x4){0.f, 0.f, 0.f, 0.f};

    const float* xrowA = X + (m0 + r) * 512 + kq * 16;
    const float* xrowB = X + (m0 + 16 + r) * 512 + kq * 16;

    // ---- prologue: stage W1 t0; xfA as two fully-issued quads ----
    STAGEW(W1t, 0, 0);
    {
        float4 q0[16], q1[16];
        #pragma unroll
        for (int f = 0; f < 4; f++)
            #pragma unroll
            for (int o = 0; o < 4; o++) {
                q0[f * 4 + o] = *(const float4*)(xrowA + f * 64 + o * 4);
                q1[f * 4 + o] = *(const float4*)(xrowA + (4 + f) * 64 + o * 4);
            }
        #pragma unroll
        for (int f = 0; f < 4; f++) {
            xfA[f]     = pack_frag(&q0[f * 4]);
            xfA[4 + f] = pack_frag(&q1[f * 4]);
        }
    }
    asm volatile("s_waitcnt vmcnt(0)" ::: "memory");
    __builtin_amdgcn_s_barrier();

    // single-rowgroup layer-1 phase (pass A or B)
    auto phase1 = [&](int nt, const i64x2* xf, i64x2* hf, f32x4* acc,
                      const u8* Wthis, const u8* Wnext) {
        const int buf = nt & 1;
        if (nt < 7) { STAGEW(Wthis, nt + 1, buf ^ 1); }
        else        { STAGEW(Wnext, 0, buf ^ 1); }
        #pragma unroll
        for (int jg = 0; jg < 4; jg++) acc[jg] = (f32x4){0.f, 0.f, 0.f, 0.f};
        __builtin_amdgcn_s_setprio(1);
        #pragma unroll
        for (int kt = 0; kt < 8; kt++)
            #pragma unroll
            for (int jg = 0; jg < 4; jg++) {
                i64x2 bfr = *(const i64x2*)&L[buf * 32768 + (kt * 4 + jg) * 1024 + l16];
                acc[jg] = MFMA8(xf[kt].x, bfr.x, acc[jg]);
                acc[jg] = MFMA8(xf[kt].y, bfr.y, acc[jg]);
            }
        __builtin_amdgcn_s_setprio(0);
        #pragma unroll
        for (int jg = 0; jg < 4; jg++)
            #pragma unroll
            for (int q = 0; q < 4; q++) {
                int row = kq * 4 + q;
                scr[row * 128 + ((jg ^ (row & 7)) << 4) + r] =
                    to_fp8(fmaxf(acc[jg][q], 0.f));
            }
        asm volatile("s_waitcnt lgkmcnt(0)" ::: "memory"); SB0();
        hf[nt] = *(const i64x2*)&scr[r * 128 + ((kq ^ (r & 7)) << 4)];
        asm volatile("s_waitcnt lgkmcnt(0)" ::: "memory"); SB0();
        asm volatile("s_waitcnt vmcnt(0)" ::: "memory");
        __builtin_amdgcn_s_barrier();
    };

    // ---- pass A with xfB streaming underneath ----
    float4 qB[16];
    #pragma unroll
    for (int f = 0; f < 4; f++)
        #pragma unroll
        for (int o = 0; o < 4; o++)
            qB[f * 4 + o] = *(const float4*)(xrowB + f * 64 + o * 4);
    #pragma unroll 1
    for (int nt = 0; nt < 4; nt++) phase1(nt, xfA, h1fA, accA, W1t, W1t);
    #pragma unroll
    for (int f = 0; f < 4; f++) xfB[f] = pack_frag(&qB[f * 4]);
    #pragma unroll
    for (int f = 0; f < 4; f++)
        #pragma unroll
        for (int o = 0; o < 4; o++)
            qB[f * 4 + o] = *(const float4*)(xrowB + (4 + f) * 64 + o * 4);
    #pragma unroll 1
    for (int nt = 4; nt < 8; nt++) phase1(nt, xfA, h1fA, accA, W1t, W1t);
    #pragma unroll
    for (int f = 0; f < 4; f++) xfB[4 + f] = pack_frag(&qB[f * 4]);

    // ---- pass B (re-staged W1; last phase prefetches W2 t0) ----
    #pragma unroll 1
    for (int nt = 0; nt < 8; nt++) phase1(nt, xfB, h1fB, accA, W1t, W2t);

    // ---- layers 2 + 3 (combined rowgroups; fused L3; r15-proven) ----
    #pragma unroll 1
    for (int nt = 0; nt < 8; nt++) {
        const int buf = nt & 1;                      // even layer-1 phase count
        if (nt < 7) STAGEW(W2t, nt + 1, buf ^ 1);
        #pragma unroll
        for (int jg = 0; jg < 4; jg++) {
            accA[jg] = (f32x4){0.f, 0.f, 0.f, 0.f};
            accB[jg] = (f32x4){0.f, 0.f, 0.f, 0.f};
        }
        __builtin_amdgcn_s_setprio(1);
        #pragma unroll
        for (int kt = 0; kt < 8; kt++)
            #pragma unroll
            for (int jg = 0; jg < 4; jg++) {
                i64x2 bfr = *(const i64x2*)&L[buf * 32768 + (kt * 4 + jg) * 1024 + l16];
                accA[jg] = MFMA8(h1fA[kt].x, bfr.x, accA[jg]);
                accA[jg] = MFMA8(h1fA[kt].y, bfr.y, accA[jg]);
                accB[jg] = MFMA8(h1fB[kt].x, bfr.x, accB[jg]);
                accB[jg] = MFMA8(h1fB[kt].y, bfr.y, accB[jg]);
            }
        __builtin_amdgcn_s_setprio(0);
        #pragma unroll
        for (int jg = 0; jg < 4; jg++)
            #pragma unroll
            for (int q = 0; q < 4; q++) {
                int rowA = kq * 4 + q;
                int rowB = 16 + kq * 4 + q;
                scr[rowA * 128 + ((jg ^ (rowA & 7)) << 4) + r] =
                    to_fp8(fmaxf(accA[jg][q], 0.f));
                scr[rowB * 128 + ((jg ^ (rowB & 7)) << 4) + r] =
                    to_fp8(fmaxf(accB[jg][q], 0.f));
            }
        asm volatile("s_waitcnt lgkmcnt(0)" ::: "memory"); SB0();
        {
            i64x2 a3A = *(const i64x2*)&scr[r * 128 + ((kq ^ (r & 7)) << 4)];
            i64x2 a3B = *(const i64x2*)&scr[(16 + r) * 128 + ((kq ^ (r & 7)) << 4)];
            i64x2 w3 = *(const i64x2*)(W3t + r * 512 + nt * 64 + kq * 16);
            yA = MFMA8(a3A.x, w3.x, yA);
            yA = MFMA8(a3A.y, w3.y, yA);
            yB = MFMA8(a3B.x, w3.x, yB);
            yB = MFMA8(a3B.y, w3.y, yB);
        }
        asm volatile("s_waitcnt lgkmcnt(0)" ::: "memory"); SB0();
        if (nt < 7) { asm volatile("s_waitcnt vmcnt(0)" ::: "memory"); }
        __builtin_amdgcn_s_barrier();
    }

    // ---- y store: direct, no atomics ----
    if (r < 10) {
        #pragma unroll
        for (int q = 0; q < 4; q++) {
            Y[(m0 + kq * 4 + q) * 10 + r]      = yA[q];
            Y[(m0 + 16 + kq * 4 + q) * 10 + r] = yB[q];
        }
    }
    #undef STAGEW
}

extern "C" void kernel_launch(void* const* d_in, const int* in_sizes, int n_in,
                              void* d_out, int out_size, void* d_ws, size_t ws_size,
                              hipStream_t stream) {
    const float* x   = (const float*)d_in[0];
    const float* mu1 = (const float*)d_in[1];
    const float* p1  = (const float*)d_in[2];
    const float* e1  = (const float*)d_in[3];
    const float* mu2 = (const float*)d_in[4];
    const float* p2  = (const float*)d_in[5];
    const float* e2  = (const float*)d_in[6];
    const float* mu3 = (const float*)d_in[7];
    const float* p3  = (const float*)d_in[8];
    const float* e3  = (const float*)d_in[9];
    float* out = (float*)d_out;

    const int B = 65536, DO = 10;

    char* ws = (char*)d_ws;
    u8* Wt1 = (u8*)(ws);            // 256 KB
    u8* Wt2 = (u8*)(ws + 262144);   // 256 KB
    u8* Wt3 = (u8*)(ws + 524288);   // 8 KB

    float* osc = out + (long)B * DO;

    hipMemsetAsync(osc, 0, 2 * sizeof(float), stream);
    hipLaunchKernelGGL(k_prep_all, dim3(1040), dim3(256), 0, stream,
                       mu1, p1, e1, mu2, p2, e2, mu3, p3, e3, Wt1, Wt2, Wt3, osc);
    hipLaunchKernelGGL(k_f8, dim3(512), dim3(256), 0, stream,
                       x, Wt1, Wt2, Wt3, out);
}

// Round 17
// 157.379 us; speedup vs baseline: 1.2954x; 1.2954x over previous
//
#include <hip/hip_runtime.h>
#include <hip/hip_bf16.h>
#include <stdint.h>

typedef unsigned char u8;
typedef unsigned int u32;
typedef unsigned long long u64;
typedef long i64;
typedef i64 i64x2 __attribute__((ext_vector_type(2)));
typedef float f32x4 __attribute__((ext_vector_type(4)));

#define LOGSQRT2PI 0.9189385332046727f
#define SB0() __builtin_amdgcn_sched_barrier(0)
#define MFMA8(A, B, C) __builtin_amdgcn_mfma_f32_16x16x32_fp8_fp8(A, B, C, 0, 0, 0)

__device__ __forceinline__ void gload_lds16(const void* g, void* l) {
    __builtin_amdgcn_global_load_lds((__attribute__((address_space(1))) void*)g,
                                     (__attribute__((address_space(3))) void*)l,
                                     16, 0, 0);
}

__device__ __forceinline__ u8 to_fp8(float v) {
    return (u8)(__builtin_amdgcn_cvt_pk_fp8_f32(v, 0.f, 0, false) & 0xff);
}

// pack 4 float4 (16 consecutive fp32) -> 16B fp8 fragment, bytes k ascending
__device__ __forceinline__ i64x2 pack_frag(const float4* v) {
    u32 w0 = __builtin_amdgcn_cvt_pk_fp8_f32(v[0].x, v[0].y, 0, false);
    w0 = __builtin_amdgcn_cvt_pk_fp8_f32(v[0].z, v[0].w, (int)w0, true);
    u32 w1 = __builtin_amdgcn_cvt_pk_fp8_f32(v[1].x, v[1].y, 0, false);
    w1 = __builtin_amdgcn_cvt_pk_fp8_f32(v[1].z, v[1].w, (int)w1, true);
    u32 w2 = __builtin_amdgcn_cvt_pk_fp8_f32(v[2].x, v[2].y, 0, false);
    w2 = __builtin_amdgcn_cvt_pk_fp8_f32(v[2].z, v[2].w, (int)w2, true);
    u32 w3 = __builtin_amdgcn_cvt_pk_fp8_f32(v[3].x, v[3].y, 0, false);
    w3 = __builtin_amdgcn_cvt_pk_fp8_f32(v[3].z, v[3].w, (int)w3, true);
    i64x2 rr;
    rr.x = (i64)(((u64)w1 << 32) | (u64)w0);
    rr.y = (i64)(((u64)w3 << 32) | (u64)w2);
    return rr;
}

// ---- merged weight prep (r15-proven, grid 528) ----
__device__ __forceinline__ void prep_body(const float* __restrict__ mu,
        const float* __restrict__ p, const float* __restrict__ eps,
        u8* __restrict__ Wt, int N, int Npad, float* __restrict__ osc,
        int vb, int nblocks) {
    int total = 512 * Npad;
    float lqw = 0.f, lpw = 0.f;
    for (int idx = vb * 256 + threadIdx.x; idx < total; idx += nblocks * 256) {
        int k = idx / Npad, n = idx - k * Npad;
        float w = 0.f;
        if (n < N) {
            int src = k * N + n;
            float m = mu[src], e = eps[src];
            float sd = 1e-6f + log1pf(expf(p[src]));
            w = m + sd * e;
            float z = (w - m) / sd;
            lqw += -LOGSQRT2PI - logf(sd) - 0.5f * z * z;
            lpw += -LOGSQRT2PI - 0.5f * w * w;
        }
        Wt[n * 512 + k] = to_fp8(w);
    }
    #pragma unroll
    for (int off = 32; off; off >>= 1) {
        lqw += __shfl_down(lqw, off);
        lpw += __shfl_down(lpw, off);
    }
    if ((threadIdx.x & 63) == 0) {
        atomicAdd(&osc[0], lqw);
        atomicAdd(&osc[1], lpw);
    }
}

__global__ void k_prep_all(const float* __restrict__ mu1, const float* __restrict__ p1,
                           const float* __restrict__ e1,
                           const float* __restrict__ mu2, const float* __restrict__ p2,
                           const float* __restrict__ e2,
                           const float* __restrict__ mu3, const float* __restrict__ p3,
                           const float* __restrict__ e3,
                           u8* __restrict__ Wt1, u8* __restrict__ Wt2,
                           u8* __restrict__ Wt3, float* __restrict__ osc) {
    int b = blockIdx.x;
    if (b < 256)      prep_body(mu1, p1, e1, Wt1, 512, 512, osc, b, 256);
    else if (b < 512) prep_body(mu2, p2, e2, Wt2, 512, 512, osc, b - 256, 256);
    else              prep_body(mu3, p3, e3, Wt3, 10,  16,  osc, b - 512, 16);
}

// ============================================================================
// Fully-fused fp8 3-layer kernel, v4: r15 skeleton at 3 blocks/CU.
//   SINGLE-buffered 64-col W-tile (32 KB) + 4x4KB scr = 48 KB LDS ->
//   3 blocks/CU = 12 waves/CU (m97's TLP regime; r15 had 8 waves/CU and its
//   dbuf was measured ~neutral, so trade dbuf for occupancy).  Phase-skewed
//   sibling blocks compute through each other's stage drains (m114 overlap).
//   launch_bounds(256,3) caps VGPR at ~170 (r15 measured ~125: no spill).
//   16 phases total, per phase: STAGE -> vmcnt(0)+barrier -> combined-rowgroup
//   GLOOP (4 MFMA per B-frag read) -> swizzled scr transpose -> h1f/L3 ->
//   barrier.  Inline x->fp8 cvt in prologue (4 sequential 64-VGPR quads).
//   h1 in registers; layer 3 fused; y stored directly (no atomics).
// ============================================================================
__global__ __launch_bounds__(256, 3)
void k_f8(const float* __restrict__ X, const u8* __restrict__ W1t,
          const u8* __restrict__ W2t, const u8* __restrict__ W3t,
          float* __restrict__ Y) {
    __shared__ __align__(16) u8 L[49152];   // 32KB Wbuf + 4x4KB scr
    const int tid = threadIdx.x;
    const int l = tid & 63, w = tid >> 6;
    const int r = l & 15, kq = l >> 4;
    const int l16 = l * 16;
    const long m0 = (long)blockIdx.x * 128 + w * 32;
    u8* scr = &L[32768 + w * 4096];

    // stage one 64-col W tile (32 chunks x 1KB; chunk = kt*4+jg): 8/thread
    #define STAGEW(WT, NT) { _Pragma("unroll")                                 \
        for (int i = 0; i < 8; i++) {                                          \
            const int c = w * 8 + i;                                           \
            const int jg = c & 3, kt = c >> 2;                                 \
            gload_lds16((WT) + ((NT) * 64 + jg * 16 + r) * 512 + kt * 64 + kq * 16, \
                        &L[c * 1024 + l16]);                                   \
        } }

    f32x4 accA[4], accB[4];
    i64x2 xfA[8], xfB[8];
    i64x2 h1fA[8], h1fB[8];
    f32x4 yA = (f32x4){0.f, 0.f, 0.f, 0.f};
    f32x4 yB = (f32x4){0.f, 0.f, 0.f, 0.f};

    const float* xrowA = X + (m0 + r) * 512 + kq * 16;
    const float* xrowB = X + (m0 + 16 + r) * 512 + kq * 16;

    // ---- prologue: x -> fp8 frags, 4 sequential 64-VGPR quads ----
    {
        float4 q[16];
        #pragma unroll
        for (int f = 0; f < 4; f++)
            #pragma unroll
            for (int o = 0; o < 4; o++)
                q[f * 4 + o] = *(const float4*)(xrowA + f * 64 + o * 4);
        #pragma unroll
        for (int f = 0; f < 4; f++) xfA[f] = pack_frag(&q[f * 4]);
        #pragma unroll
        for (int f = 0; f < 4; f++)
            #pragma unroll
            for (int o = 0; o < 4; o++)
                q[f * 4 + o] = *(const float4*)(xrowA + (4 + f) * 64 + o * 4);
        #pragma unroll
        for (int f = 0; f < 4; f++) xfA[4 + f] = pack_frag(&q[f * 4]);
        #pragma unroll
        for (int f = 0; f < 4; f++)
            #pragma unroll
            for (int o = 0; o < 4; o++)
                q[f * 4 + o] = *(const float4*)(xrowB + f * 64 + o * 4);
        #pragma unroll
        for (int f = 0; f < 4; f++) xfB[f] = pack_frag(&q[f * 4]);
        #pragma unroll
        for (int f = 0; f < 4; f++)
            #pragma unroll
            for (int o = 0; o < 4; o++)
                q[f * 4 + o] = *(const float4*)(xrowB + (4 + f) * 64 + o * 4);
        #pragma unroll
        for (int f = 0; f < 4; f++) xfB[4 + f] = pack_frag(&q[f * 4]);
    }

    // ================= layer 1 (8 x 64-col tiles) =================
    #pragma unroll 1
    for (int nt = 0; nt < 8; nt++) {
        STAGEW(W1t, nt);
        asm volatile("s_waitcnt vmcnt(0)" ::: "memory");
        __builtin_amdgcn_s_barrier();
        #pragma unroll
        for (int jg = 0; jg < 4; jg++) {
            accA[jg] = (f32x4){0.f, 0.f, 0.f, 0.f};
            accB[jg] = (f32x4){0.f, 0.f, 0.f, 0.f};
        }
        #pragma unroll
        for (int kt = 0; kt < 8; kt++)
            #pragma unroll
            for (int jg = 0; jg < 4; jg++) {
                i64x2 bfr = *(const i64x2*)&L[(kt * 4 + jg) * 1024 + l16];
                accA[jg] = MFMA8(xfA[kt].x, bfr.x, accA[jg]);
                accA[jg] = MFMA8(xfA[kt].y, bfr.y, accA[jg]);
                accB[jg] = MFMA8(xfB[kt].x, bfr.x, accB[jg]);
                accB[jg] = MFMA8(xfB[kt].y, bfr.y, accB[jg]);
            }
        #pragma unroll
        for (int jg = 0; jg < 4; jg++)
            #pragma unroll
            for (int q = 0; q < 4; q++) {
                int rowA = kq * 4 + q;
                int rowB = 16 + kq * 4 + q;
                scr[rowA * 128 + ((jg ^ (rowA & 7)) << 4) + r] =
                    to_fp8(fmaxf(accA[jg][q], 0.f));
                scr[rowB * 128 + ((jg ^ (rowB & 7)) << 4) + r] =
                    to_fp8(fmaxf(accB[jg][q], 0.f));
            }
        asm volatile("s_waitcnt lgkmcnt(0)" ::: "memory"); SB0();
        h1fA[nt] = *(const i64x2*)&scr[r * 128 + ((kq ^ (r & 7)) << 4)];
        h1fB[nt] = *(const i64x2*)&scr[(16 + r) * 128 + ((kq ^ (r & 7)) << 4)];
        asm volatile("s_waitcnt lgkmcnt(0)" ::: "memory"); SB0();
        __builtin_amdgcn_s_barrier();   // all reads done before next stage
    }

    // ================= layers 2 + 3 (8 x 64-col tiles) =================
    #pragma unroll 1
    for (int nt = 0; nt < 8; nt++) {
        STAGEW(W2t, nt);
        asm volatile("s_waitcnt vmcnt(0)" ::: "memory");
        __builtin_amdgcn_s_barrier();
        #pragma unroll
        for (int jg = 0; jg < 4; jg++) {
            accA[jg] = (f32x4){0.f, 0.f, 0.f, 0.f};
            accB[jg] = (f32x4){0.f, 0.f, 0.f, 0.f};
        }
        #pragma unroll
        for (int kt = 0; kt < 8; kt++)
            #pragma unroll
            for (int jg = 0; jg < 4; jg++) {
                i64x2 bfr = *(const i64x2*)&L[(kt * 4 + jg) * 1024 + l16];
                accA[jg] = MFMA8(h1fA[kt].x, bfr.x, accA[jg]);
                accA[jg] = MFMA8(h1fA[kt].y, bfr.y, accA[jg]);
                accB[jg] = MFMA8(h1fB[kt].x, bfr.x, accB[jg]);
                accB[jg] = MFMA8(h1fB[kt].y, bfr.y, accB[jg]);
            }
        #pragma unroll
        for (int jg = 0; jg < 4; jg++)
            #pragma unroll
            for (int q = 0; q < 4; q++) {
                int rowA = kq * 4 + q;
                int rowB = 16 + kq * 4 + q;
                scr[rowA * 128 + ((jg ^ (rowA & 7)) << 4) + r] =
                    to_fp8(fmaxf(accA[jg][q], 0.f));
                scr[rowB * 128 + ((jg ^ (rowB & 7)) << 4) + r] =
                    to_fp8(fmaxf(accB[jg][q], 0.f));
            }
        asm volatile("s_waitcnt lgkmcnt(0)" ::: "memory"); SB0();
        {
            i64x2 a3A = *(const i64x2*)&scr[r * 128 + ((kq ^ (r & 7)) << 4)];
            i64x2 a3B = *(const i64x2*)&scr[(16 + r) * 128 + ((kq ^ (r & 7)) << 4)];
            i64x2 w3 = *(const i64x2*)(W3t + r * 512 + nt * 64 + kq * 16);
            yA = MFMA8(a3A.x, w3.x, yA);
            yA = MFMA8(a3A.y, w3.y, yA);
            yB = MFMA8(a3B.x, w3.x, yB);
            yB = MFMA8(a3B.y, w3.y, yB);
        }
        asm volatile("s_waitcnt lgkmcnt(0)" ::: "memory"); SB0();
        __builtin_amdgcn_s_barrier();
    }

    // ---- y store: direct, no atomics ----
    if (r < 10) {
        #pragma unroll
        for (int q = 0; q < 4; q++) {
            Y[(m0 + kq * 4 + q) * 10 + r]      = yA[q];
            Y[(m0 + 16 + kq * 4 + q) * 10 + r] = yB[q];
        }
    }
    #undef STAGEW
}

extern "C" void kernel_launch(void* const* d_in, const int* in_sizes, int n_in,
                              void* d_out, int out_size, void* d_ws, size_t ws_size,
                              hipStream_t stream) {
    const float* x   = (const float*)d_in[0];
    const float* mu1 = (const float*)d_in[1];
    const float* p1  = (const float*)d_in[2];
    const float* e1  = (const float*)d_in[3];
    const float* mu2 = (const float*)d_in[4];
    const float* p2  = (const float*)d_in[5];
    const float* e2  = (const float*)d_in[6];
    const float* mu3 = (const float*)d_in[7];
    const float* p3  = (const float*)d_in[8];
    const float* e3  = (const float*)d_in[9];
    float* out = (float*)d_out;

    const int B = 65536, DO = 10;

    char* ws = (char*)d_ws;
    u8* Wt1 = (u8*)(ws);            // 256 KB
    u8* Wt2 = (u8*)(ws + 262144);   // 256 KB
    u8* Wt3 = (u8*)(ws + 524288);   // 8 KB

    float* osc = out + (long)B * DO;

    hipMemsetAsync(osc, 0, 2 * sizeof(float), stream);
    hipLaunchKernelGGL(k_prep_all, dim3(528), dim3(256), 0, stream,
                       mu1, p1, e1, mu2, p2, e2, mu3, p3, e3, Wt1, Wt2, Wt3, osc);
    hipLaunchKernelGGL(k_f8, dim3(512), dim3(256), 0, stream,
                       x, Wt1, Wt2, Wt3, out);
}